// Round 3
// baseline (1595.589 us; speedup 1.0000x reference)
//
#include <hip/hip_runtime.h>
#include <hip/hip_bf16.h>
#include <stdint.h>

#define N_NODES 10000
#define N_EDGES 640000
#define KPAD    10016   // K=10000 padded to mult of 32 for B staging

typedef __bf16 bf16x8 __attribute__((ext_vector_type(8)));
typedef float  f32x4  __attribute__((ext_vector_type(4)));

// ---- workspace layout (bytes) ----
#define OFF_CNT   0          // 10000 ints
#define OFF_FLAG  40960      // 1 int (int64-sniff flag)
#define OFF_DINV  65536      // 10000 floats
#define OFF_RS    131072     // 10001 ints (row_start)
#define OFF_CUR   196608     // 10000 ints (cursor)
#define OFF_CSR   262144     // 640000 ints
#define OFF_H1    3145728    // 10000*256 fp32 (written by gemm, full coverage)
#define OFF_EMBT  14155776   // 256*KPAD bf16; reused for g1 after GEMM1
#define OFF_G2    16777216   // 10000*32 fp32
#define OFF_H2    19922944   // 10000*64 fp32
#define OFF_H3    22544384   // 10000*32 fp32

__device__ __forceinline__ unsigned short f2b(float f) {   // fp32 -> bf16 RNE
    unsigned int v = __float_as_uint(f);
    unsigned int r = (v + 0x7FFFu + ((v >> 16) & 1u)) >> 16;
    return (unsigned short)r;
}

// Detect int64 edge_index layout: if odd int32 words of the first 128 entries are
// all zero, data is little-endian int64 (values in [0,10000) -> high words 0).
__global__ void k_sniff(const int* __restrict__ edge, int* __restrict__ flag) {
    if (threadIdx.x == 0 && blockIdx.x == 0) {
        int f = 1;
        for (int i = 1; i < 256; i += 2) if (edge[i] != 0) { f = 0; break; }
        *flag = f;
    }
}

__global__ void k_count(const int* __restrict__ edge, const int* __restrict__ flag,
                        int* __restrict__ cnt) {
    int e = blockIdx.x * 256 + threadIdx.x;   // grid exactly 640000 threads
    int f = *flag;
    const int* dstp = edge + (f ? 2 * N_EDGES : N_EDGES);
    atomicAdd(&cnt[dstp[e << f]], 1);
}

__global__ void k_dinv(const int* __restrict__ cnt, float* __restrict__ dinv) {
    int i = blockIdx.x * 256 + threadIdx.x;
    if (i < N_NODES) dinv[i] = rsqrtf((float)(cnt[i] + 1));  // +1 self-loop
}

__global__ void k_scan(const int* __restrict__ cnt, int* __restrict__ rs, int* __restrict__ cur) {
    __shared__ int buf[256];
    __shared__ int carry;
    int tid = threadIdx.x;
    if (tid == 0) { carry = 0; rs[0] = 0; }
    __syncthreads();
    for (int base = 0; base < N_NODES; base += 256) {
        int i = base + tid;
        int v = (i < N_NODES) ? cnt[i] : 0;
        buf[tid] = v;
        __syncthreads();
        for (int off = 1; off < 256; off <<= 1) {
            int t = (tid >= off) ? buf[tid - off] : 0;
            __syncthreads();
            buf[tid] += t;
            __syncthreads();
        }
        int incl = buf[tid] + carry;
        if (i < N_NODES) { rs[i + 1] = incl; cur[i] = incl - v; }
        __syncthreads();
        if (tid == 255) carry = incl;
        __syncthreads();
    }
}

__global__ void k_fill(const int* __restrict__ edge, const int* __restrict__ flag,
                       int* __restrict__ cur, int* __restrict__ csr) {
    int e = blockIdx.x * 256 + threadIdx.x;
    int f = *flag;
    const int* srcp = edge;
    const int* dstp = edge + (f ? 2 * N_EDGES : N_EDGES);
    int s = srcp[e << f];
    int d = dstp[e << f];
    int pos = atomicAdd(&cur[d], 1);
    csr[pos] = s;
}

__global__ void k_padzero(unsigned short* __restrict__ embT) {
    int i = blockIdx.x * 256 + threadIdx.x;   // 4096 total
    if (i < 256 * 16) {
        int n = i >> 4, k = i & 15;
        embT[(size_t)n * KPAD + 10000 + k] = 0;
    }
}

// emb [10000,256] fp32 -> embT [256,KPAD] bf16, LDS tile transpose
__global__ void k_transpose(const float* __restrict__ emb, unsigned short* __restrict__ embT) {
    __shared__ unsigned short t[32][65];
    int r0 = blockIdx.x * 32, c0 = blockIdx.y * 64;
    int cl = threadIdx.x & 63, rl = threadIdx.x >> 6;   // rl 0..3
    for (int i = 0; i < 8; ++i) {
        int r = r0 + rl + i * 4;
        if (r < N_NODES) t[rl + i * 4][cl] = f2b(emb[(size_t)r * 256 + c0 + cl]);
    }
    __syncthreads();
    int rr = threadIdx.x & 31, cc0 = threadIdx.x >> 5;  // cc0 0..7
    int r = r0 + rr;
    if (r < N_NODES) {
        for (int j = 0; j < 8; ++j) {
            int c = cc0 * 8 + j;
            embT[(size_t)(c0 + c) * KPAD + r] = t[rr][c];
        }
    }
}

// ---- GEMM1: H1 = X[10000,10000]fp32 @ emb[10000,256]  (pre-relu, fp32 out) ----
// BM=32 BN=256 BK=32; grid (313); 4 waves, each 32 rows x 64 cols (2x4 MFMA tiles).
// A is converted fp32->bf16 during staging; X read exactly once (400 MB).
#define LDK 40

__global__ __launch_bounds__(256, 4) void k_gemm1(
        const float* __restrict__ X,
        const unsigned short* __restrict__ embT,
        float* __restrict__ H1) {
    __shared__ __align__(16) unsigned short As[32 * LDK];
    __shared__ __align__(16) unsigned short Bs[256 * LDK];
    const int tid = threadIdx.x;
    const int lane = tid & 63;
    const int w = tid >> 6;                  // wave 0..3 -> 64-col slice
    const int bM = blockIdx.x;

    // A staging: 256 threads, row tid>>3 (0..31), chunk tid&7 (4 floats each)
    const int ar = tid >> 3, ac = tid & 7;
    int agrow = bM * 32 + ar; if (agrow > N_NODES - 1) agrow = N_NODES - 1;
    const float* gA = X + (size_t)agrow * 10000 + ac * 4;
    // B staging: 256 threads x 4 uint4: rows tid>>2 + {0,64,128,192}, chunk tid&3
    const int br = tid >> 2, bc = tid & 3;
    const unsigned short* gB = embT + (size_t)br * KPAD + bc * 8;

    float4 pa = *(const float4*)(gA);
    uint4 pb[4];
#pragma unroll
    for (int s = 0; s < 4; ++s) pb[s] = *(const uint4*)(gB + (size_t)(64 * s) * KPAD);

    f32x4 acc[2][4];
#pragma unroll
    for (int i = 0; i < 2; ++i)
#pragma unroll
        for (int j = 0; j < 4; ++j) acc[i][j] = (f32x4){0.f, 0.f, 0.f, 0.f};

    const int q = lane >> 4, l16 = lane & 15;
    const unsigned short* aRd0 = As + l16 * LDK + q * 8;
    const unsigned short* aRd1 = As + (16 + l16) * LDK + q * 8;
    const unsigned short* bRd[4];
#pragma unroll
    for (int nt = 0; nt < 4; ++nt) bRd[nt] = Bs + (w * 64 + nt * 16 + l16) * LDK + q * 8;

    for (int it = 0; it < 313; ++it) {
        __syncthreads();
        {
            ushort4 av;
            av.x = f2b(pa.x); av.y = f2b(pa.y); av.z = f2b(pa.z); av.w = f2b(pa.w);
            *(ushort4*)(As + ar * LDK + ac * 4) = av;
#pragma unroll
            for (int s = 0; s < 4; ++s)
                *(uint4*)(Bs + (br + 64 * s) * LDK + bc * 8) = pb[s];
        }
        __syncthreads();
        if (it + 1 < 313) {
            const int kk = (it + 1) * 32;
            // A tail: last iter covers k 9984..9999; chunks with k+4 > 10000 -> 0
            pa = (kk + ac * 4 + 4 <= 10000) ? *(const float4*)(gA + kk)
                                            : make_float4(0.f, 0.f, 0.f, 0.f);
#pragma unroll
            for (int s = 0; s < 4; ++s)     // embT zero-padded to KPAD -> always safe
                pb[s] = *(const uint4*)(gB + (size_t)(64 * s) * KPAD + kk);
        }
        bf16x8 a0 = *(const bf16x8*)aRd0;
        bf16x8 a1 = *(const bf16x8*)aRd1;
        bf16x8 bf[4];
#pragma unroll
        for (int nt = 0; nt < 4; ++nt) bf[nt] = *(const bf16x8*)bRd[nt];
#pragma unroll
        for (int nt = 0; nt < 4; ++nt) {
            acc[0][nt] = __builtin_amdgcn_mfma_f32_16x16x32_bf16(a0, bf[nt], acc[0][nt], 0, 0, 0);
            acc[1][nt] = __builtin_amdgcn_mfma_f32_16x16x32_bf16(a1, bf[nt], acc[1][nt], 0, 0, 0);
        }
    }

    // epilogue: C/D layout col=lane&15, row=(lane>>4)*4+reg  [m89/m91-verified]
#pragma unroll
    for (int mt = 0; mt < 2; ++mt)
#pragma unroll
        for (int nt = 0; nt < 4; ++nt) {
            int col = w * 64 + nt * 16 + l16;
            int rbase = bM * 32 + mt * 16 + q * 4;
#pragma unroll
            for (int r = 0; r < 4; ++r) {
                int row = rbase + r;
                if (row < N_NODES) H1[(size_t)row * 256 + col] = acc[mt][nt][r];
            }
        }
}

// g1[n,f] = dinv[n] * sum_k relu(H1[n,k]) * W1[k,f]   (relu applied on read)
__global__ void k_lin1(const float* __restrict__ H1, const float* __restrict__ W1,
                       const float* __restrict__ dinv, float* __restrict__ g1) {
    __shared__ float w1s[256 * 64];   // 64 KB
    int tid = threadIdx.x;
    for (int i = tid; i < 256 * 64; i += 256) w1s[i] = W1[i];
    __syncthreads();
    int f = tid & 63, nl = tid >> 6;
    int node = blockIdx.x * 4 + nl;
    const float* h = H1 + (size_t)node * 256;
    float acc = 0.f;
#pragma unroll 4
    for (int k = 0; k < 256; ++k) acc += fmaxf(h[k], 0.f) * w1s[k * 64 + f];
    g1[(size_t)node * 64 + f] = acc * dinv[node];
}

// H2[n,f] = relu( dinv[n]*(g1[n,f] + sum_{s->n} g1[s,f]) + b1[f] )
__global__ void k_agg1(const float* __restrict__ g1, const int* __restrict__ rs,
                       const int* __restrict__ csr, const float* __restrict__ dinv,
                       const float* __restrict__ b1, float* __restrict__ H2) {
    int lane = threadIdx.x & 63;
    int node = blockIdx.x * 4 + (threadIdx.x >> 6);
    float acc = g1[(size_t)node * 64 + lane];
    int e0 = rs[node], e1 = rs[node + 1];
    for (int e = e0; e < e1; ++e) acc += g1[(size_t)csr[e] * 64 + lane];
    float o = dinv[node] * acc + b1[lane];
    H2[(size_t)node * 64 + lane] = fmaxf(o, 0.f);
}

__global__ void k_lin2(const float* __restrict__ H2, const float* __restrict__ W2,
                       const float* __restrict__ dinv, float* __restrict__ g2) {
    __shared__ float w2s[64 * 32];
    int tid = threadIdx.x;
    for (int i = tid; i < 64 * 32; i += 256) w2s[i] = W2[i];
    __syncthreads();
    int f = tid & 31, nl = tid >> 5;
    int node = blockIdx.x * 8 + nl;
    const float* h = H2 + (size_t)node * 64;
    float acc = 0.f;
#pragma unroll
    for (int k = 0; k < 64; ++k) acc += h[k] * w2s[k * 32 + f];
    g2[(size_t)node * 32 + f] = acc * dinv[node];
}

__global__ void k_agg2(const float* __restrict__ g2, const int* __restrict__ rs,
                       const int* __restrict__ csr, const float* __restrict__ dinv,
                       const float* __restrict__ b2, float* __restrict__ H3) {
    int lane = threadIdx.x & 63;
    int node = blockIdx.x * 4 + (threadIdx.x >> 6);
    int f = lane & 31, half = lane >> 5;
    int e0 = rs[node], e1 = rs[node + 1];
    float acc = 0.f;
    for (int e = e0 + half; e < e1; e += 2) acc += g2[(size_t)csr[e] * 32 + f];
    acc += __shfl_down(acc, 32);
    if (half == 0) {
        acc += g2[(size_t)node * 32 + f];
        float o = dinv[node] * acc + b2[f];
        H3[(size_t)node * 32 + f] = fmaxf(o, 0.f);
    }
}

__global__ void k_dec(const float* __restrict__ H3, const float* __restrict__ dW,
                      float* __restrict__ out) {
    __shared__ float dws[32 * 16];
    int tid = threadIdx.x;
    for (int i = tid; i < 512; i += 256) dws[i] = dW[i];
    __syncthreads();
    int j = tid & 15, nl = tid >> 4;
    int node = blockIdx.x * 16 + nl;
    const float* h = H3 + (size_t)node * 32;
    float acc = 0.f;
#pragma unroll
    for (int k = 0; k < 32; ++k) acc += h[k] * dws[k * 16 + j];
    out[(size_t)node * 16 + j] = acc;
}

extern "C" void kernel_launch(void* const* d_in, const int* in_sizes, int n_in,
                              void* d_out, int out_size, void* d_ws, size_t ws_size,
                              hipStream_t stream) {
    const float* X    = (const float*)d_in[0];
    const int*   edge = (const int*)d_in[1];
    const float* emb  = (const float*)d_in[2];
    const float* W1   = (const float*)d_in[3];
    const float* b1   = (const float*)d_in[4];
    const float* W2   = (const float*)d_in[5];
    const float* b2   = (const float*)d_in[6];
    const float* dW   = (const float*)d_in[7];
    float*       out  = (float*)d_out;

    char* ws = (char*)d_ws;
    int*            cnt  = (int*)(ws + OFF_CNT);
    int*            flag = (int*)(ws + OFF_FLAG);
    float*          dinv = (float*)(ws + OFF_DINV);
    int*            rs   = (int*)(ws + OFF_RS);
    int*            cur  = (int*)(ws + OFF_CUR);
    int*            csr  = (int*)(ws + OFF_CSR);
    float*          H1   = (float*)(ws + OFF_H1);
    unsigned short* embT = (unsigned short*)(ws + OFF_EMBT);
    float*          g1   = (float*)(ws + OFF_EMBT);  // reuse after GEMM1 consumed embT
    float*          g2   = (float*)(ws + OFF_G2);
    float*          H2   = (float*)(ws + OFF_H2);
    float*          H3   = (float*)(ws + OFF_H3);

    hipMemsetAsync(cnt, 0, N_NODES * sizeof(int), stream);

    k_sniff<<<1, 64, 0, stream>>>(edge, flag);
    k_count<<<N_EDGES / 256, 256, 0, stream>>>(edge, flag, cnt);
    k_dinv<<<(N_NODES + 255) / 256, 256, 0, stream>>>(cnt, dinv);
    k_scan<<<1, 256, 0, stream>>>(cnt, rs, cur);
    k_fill<<<N_EDGES / 256, 256, 0, stream>>>(edge, flag, cur, csr);
    k_padzero<<<16, 256, 0, stream>>>(embT);
    k_transpose<<<dim3(313, 4), 256, 0, stream>>>(emb, embT);
    k_gemm1<<<dim3(313), 256, 0, stream>>>(X, embT, H1);
    k_lin1<<<N_NODES / 4, 256, 0, stream>>>(H1, W1, dinv, g1);
    k_agg1<<<N_NODES / 4, 256, 0, stream>>>(g1, rs, csr, dinv, b1, H2);
    k_lin2<<<N_NODES / 8, 256, 0, stream>>>(H2, W2, dinv, g2);
    k_agg2<<<N_NODES / 4, 256, 0, stream>>>(g2, rs, csr, dinv, b2, H3);
    k_dec<<<N_NODES / 16, 256, 0, stream>>>(H3, dW, out);
}